// Round 3
// baseline (217.024 us; speedup 1.0000x reference)
//
#include <hip/hip_runtime.h>
#include <hip/hip_bf16.h>

#define N_NODES 16000
#define IN_F 128
#define HID 64
#define BATCH 32
#define NPAIR 128
#define DRES 100
#define NCLS 10

// workspace layout (float offsets)
#define NF_OFF     0
#define WT1_OFF    16000                 // [2 ic][25 tap][16 oc] = 800
#define WT2_OFF    (16000 + 800)         // [16 ic][25 tap][32 oc] = 12800
#define IMGSP_OFF  (16000 + 800 + 12800) // [32][2][104][104] padded (+2 border)
#define POOL1P_OFF (IMGSP_OFF + 32*2*104*104)      // [32][16][54][56] padded (+2 border)
#define POOL2_OFF  (POOL1P_OFF + 32*16*54*56)      // [32][32][25][25]
#define ZERO_N4    ((32*2*104*104 + 32*16*54*56) / 4)

// ---------------- Kernel W: weight transpose (runs once per launch) ----------------
__global__ __launch_bounds__(256) void k_wt(const float* __restrict__ c1w,
    const float* __restrict__ c2w, float* __restrict__ wT1, float* __restrict__ wT2)
{
    int t = blockIdx.x * 256 + threadIdx.x;
    // wT1[ic][tap][oc] <- c1w[oc][ic][tap]   (16 oc, 2 ic, 25 tap)
    for (int i = t; i < 800; i += 256 * 8) {
        int ic = i / 400, tap = (i / 16) % 25, oc = i % 16;
        wT1[i] = c1w[(oc * 2 + ic) * 25 + tap];
    }
    // wT2[ic][tap][oc] <- c2w[oc][ic][tap]   (32 oc, 16 ic, 25 tap)
    for (int i = t; i < 12800; i += 256 * 8) {
        int ic = i / 800, tap = (i / 32) % 25, oc = i % 32;
        wT2[i] = c2w[(oc * 16 + ic) * 25 + tap];
    }
}

// ---------------- Kernel Z: zero padded activation buffers ----------------
__global__ __launch_bounds__(256) void k_zero(float* __restrict__ dst)
{
    int i = blockIdx.x * 256 + threadIdx.x;
    if (i < ZERO_N4) ((float4*)dst)[i] = make_float4(0.f, 0.f, 0.f, 0.f);
}

// ---------------- Kernel A: node filtration MLP ----------------
__global__ __launch_bounds__(256) void k_filt(const float* __restrict__ x,
    const float* __restrict__ w1, const float* __restrict__ b1,
    const float* __restrict__ w2, const float* __restrict__ b2,
    float* __restrict__ nf, float* __restrict__ out_nf)
{
    int t = threadIdx.x;
    int wave = t >> 6, lane = t & 63;
    int n = blockIdx.x * 4 + wave;
    if (n >= N_NODES) return;
    const float* xr = x + (size_t)n * IN_F;
    float acc = b1[lane];
    #pragma unroll 8
    for (int k = 0; k < IN_F; ++k)
        acc += xr[k] * w1[k * HID + lane];
    float h = fmaxf(acc, 0.f);
    float p = h * w2[lane];
    #pragma unroll
    for (int off = 32; off > 0; off >>= 1)
        p += __shfl_down(p, off, 64);
    if (lane == 0) {
        float s = p + b2[0];
        float f = 1.f / (1.f + expf(-s));
        nf[n] = f;
        out_nf[n] = f;
    }
}

// ---------------- Kernel B: persistence image (writes padded imgs) ----------------
__global__ __launch_bounds__(256) void k_pimg(const float* __restrict__ nf,
    const int* __restrict__ pi0, const int* __restrict__ pi1,
    float* __restrict__ imgs_p)
{
    int b = blockIdx.x >> 1, c = blockIdx.x & 1;
    const int* pi = c ? pi1 : pi0;
    __shared__ float sb[NPAIR], sp[NPAIR];
    __shared__ float wmax[4];
    int t = threadIdx.x;
    if (t < NPAIR) {
        int i0 = pi[(b * NPAIR + t) * 2 + 0];
        int i1 = pi[(b * NPAIR + t) * 2 + 1];
        float f0 = nf[i0], f1 = nf[i1];
        sb[t] = f0;
        sp[t] = f1 - f0;
    }
    __syncthreads();

    int ti = t / 13, tj = t % 13;
    float ci[8], cj[8];
    #pragma unroll
    for (int r = 0; r < 8; ++r) {
        ci[r] = (float)(ti + 13 * r) * 0.01f;
        cj[r] = (float)(tj + 13 * r) * 0.01f;
    }
    float acc[8][8];
    #pragma unroll
    for (int r = 0; r < 8; ++r)
        #pragma unroll
        for (int s = 0; s < 8; ++s) acc[r][s] = 0.f;

    for (int p = 0; p < NPAIR; ++p) {
        float bb = sb[p], pp = sp[p];
        float eb[8], ep[8];
        #pragma unroll
        for (int r = 0; r < 8; ++r) { float d = bb - ci[r]; eb[r] = __expf(-d * d); }
        #pragma unroll
        for (int s = 0; s < 8; ++s) { float d = pp - cj[s]; ep[s] = __expf(-d * d); }
        #pragma unroll
        for (int r = 0; r < 8; ++r)
            #pragma unroll
            for (int s = 0; s < 8; ++s)
                acc[r][s] += eb[r] * ep[s];
    }

    bool active = t < 169;
    float lmax = 0.f;
    if (active) {
        #pragma unroll
        for (int r = 0; r < 8; ++r) {
            if (ti + 13 * r < DRES) {
                #pragma unroll
                for (int s = 0; s < 8; ++s)
                    if (tj + 13 * s < DRES) lmax = fmaxf(lmax, acc[r][s]);
            }
        }
    }
    #pragma unroll
    for (int off = 32; off > 0; off >>= 1)
        lmax = fmaxf(lmax, __shfl_xor(lmax, off, 64));
    if ((t & 63) == 0) wmax[t >> 6] = lmax;
    __syncthreads();
    float bmax = fmaxf(fmaxf(wmax[0], wmax[1]), fmaxf(wmax[2], wmax[3]));
    float inv = 1.f / bmax;
    if (active) {
        float* dst = imgs_p + (((size_t)(b * 2 + c) * 104 + 2) * 104 + 2);
        #pragma unroll
        for (int r = 0; r < 8; ++r) {
            int i = ti + 13 * r;
            if (i < DRES) {
                #pragma unroll
                for (int s = 0; s < 8; ++s) {
                    int j = tj + 13 * s;
                    if (j < DRES) dst[i * 104 + j] = acc[r][s] * inv;
                }
            }
        }
    }
}

// ---------------- Kernel C: conv1 (2->16) + relu + maxpool2, no LDS ----------------
// thread = 4 oc x 1 pooled output. 320000 threads = 1250 blocks x 256.
__global__ __launch_bounds__(256) void k_conv1(const float* __restrict__ imgs_p,
    const float* __restrict__ wT1, const float* __restrict__ cb,
    float* __restrict__ pool1p)
{
    int g = blockIdx.x * 256 + threadIdx.x;
    int ow = g % 50, oh = (g / 50) % 50, ocg = (g / 2500) % 4, b = g / 10000;
    float acc[4][2][2] = {};
    for (int ic = 0; ic < 2; ++ic) {
        const float* base = imgs_p + (((size_t)(b * 2 + ic) * 104 + 2 * oh) * 104 + 2 * ow);
        float p[6][6];
        #pragma unroll
        for (int r = 0; r < 6; ++r) {
            const float* rp = base + r * 104;
            float2 a = *(const float2*)(rp);
            float2 m = *(const float2*)(rp + 2);
            float2 e = *(const float2*)(rp + 4);
            p[r][0] = a.x; p[r][1] = a.y; p[r][2] = m.x;
            p[r][3] = m.y; p[r][4] = e.x; p[r][5] = e.y;
        }
        const float* wrow = wT1 + ic * 400 + ocg * 4;
        #pragma unroll
        for (int kh = 0; kh < 5; ++kh)
            #pragma unroll
            for (int kw = 0; kw < 5; ++kw) {
                float4 wv = *(const float4*)(wrow + (kh * 5 + kw) * 16);
                #pragma unroll
                for (int py = 0; py < 2; ++py)
                    #pragma unroll
                    for (int px = 0; px < 2; ++px) {
                        float v = p[kh + py][kw + px];
                        acc[0][py][px] += v * wv.x;
                        acc[1][py][px] += v * wv.y;
                        acc[2][py][px] += v * wv.z;
                        acc[3][py][px] += v * wv.w;
                    }
            }
    }
    float4 bias = *(const float4*)(cb + ocg * 4);
    float bv[4] = {bias.x, bias.y, bias.z, bias.w};
    #pragma unroll
    for (int o = 0; o < 4; ++o) {
        float m = fmaxf(fmaxf(acc[o][0][0], acc[o][0][1]),
                        fmaxf(acc[o][1][0], acc[o][1][1]));
        float res = fmaxf(m + bv[o], 0.f);
        // padded pool1p: [b][oc][54][56], interior at +2,+2
        pool1p[(((size_t)(b * 16 + ocg * 4 + o) * 54) + oh + 2) * 56 + ow + 2] = res;
    }
}

// ---------------- Kernel D: conv2 (16->32) + relu + maxpool2, no LDS ----------------
// thread = 4 oc x 1 pooled output. 160000 threads = 2500 blocks x 64.
__global__ __launch_bounds__(64) void k_conv2(const float* __restrict__ pool1p,
    const float* __restrict__ wT2, const float* __restrict__ cb,
    float* __restrict__ pool2)
{
    int g = blockIdx.x * 64 + threadIdx.x;
    int ow = g % 25, oh = (g / 25) % 25, ocg = (g / 625) % 8, b = g / 5000;
    float acc[4][2][2] = {};
    for (int ic = 0; ic < 16; ++ic) {
        const float* base = pool1p + (((size_t)(b * 16 + ic) * 54 + 2 * oh) * 56 + 2 * ow);
        float p[6][6];
        #pragma unroll
        for (int r = 0; r < 6; ++r) {
            const float* rp = base + r * 56;
            float2 a = *(const float2*)(rp);
            float2 m = *(const float2*)(rp + 2);
            float2 e = *(const float2*)(rp + 4);
            p[r][0] = a.x; p[r][1] = a.y; p[r][2] = m.x;
            p[r][3] = m.y; p[r][4] = e.x; p[r][5] = e.y;
        }
        const float* wrow = wT2 + ic * 800 + ocg * 4;
        #pragma unroll
        for (int kh = 0; kh < 5; ++kh)
            #pragma unroll
            for (int kw = 0; kw < 5; ++kw) {
                float4 wv = *(const float4*)(wrow + (kh * 5 + kw) * 32);
                #pragma unroll
                for (int py = 0; py < 2; ++py)
                    #pragma unroll
                    for (int px = 0; px < 2; ++px) {
                        float v = p[kh + py][kw + px];
                        acc[0][py][px] += v * wv.x;
                        acc[1][py][px] += v * wv.y;
                        acc[2][py][px] += v * wv.z;
                        acc[3][py][px] += v * wv.w;
                    }
            }
    }
    float4 bias = *(const float4*)(cb + ocg * 4);
    float bv[4] = {bias.x, bias.y, bias.z, bias.w};
    #pragma unroll
    for (int o = 0; o < 4; ++o) {
        float m = fmaxf(fmaxf(acc[o][0][0], acc[o][0][1]),
                        fmaxf(acc[o][1][0], acc[o][1][1]));
        float res = fmaxf(m + bv[o], 0.f);
        pool2[((size_t)(b * 32 + ocg * 4 + o) * 25 + oh) * 25 + ow] = res;
    }
}

// ---------------- Kernel E: final linear ----------------
__global__ __launch_bounds__(256) void k_fc(const float* __restrict__ pool2,
    const float* __restrict__ oww, const float* __restrict__ ob,
    float* __restrict__ yhat)
{
    int b = blockIdx.x / NCLS, cls = blockIdx.x % NCLS;
    int t = threadIdx.x;
    const float* y = pool2 + (size_t)b * 20000;
    const float* w = oww + (size_t)cls * 20000;
    float acc = 0.f;
    for (int k = t; k < 20000; k += 256)
        acc += y[k] * w[k];
    #pragma unroll
    for (int off = 32; off > 0; off >>= 1)
        acc += __shfl_down(acc, off, 64);
    __shared__ float part[4];
    if ((t & 63) == 0) part[t >> 6] = acc;
    __syncthreads();
    if (t == 0) {
        float s = part[0] + part[1] + part[2] + part[3] + ob[cls];
        yhat[b * NCLS + cls] = s;
    }
}

extern "C" void kernel_launch(void* const* d_in, const int* in_sizes, int n_in,
                              void* d_out, int out_size, void* d_ws, size_t ws_size,
                              hipStream_t stream)
{
    const float* x   = (const float*)d_in[0];
    const int*   pi0 = (const int*)d_in[1];
    const int*   pi1 = (const int*)d_in[2];
    const float* w1  = (const float*)d_in[3];
    const float* b1  = (const float*)d_in[4];
    const float* w2  = (const float*)d_in[5];
    const float* b2  = (const float*)d_in[6];
    const float* c1w = (const float*)d_in[7];
    const float* c1b = (const float*)d_in[8];
    const float* c2w = (const float*)d_in[9];
    const float* c2b = (const float*)d_in[10];
    const float* oww = (const float*)d_in[11];
    const float* owb = (const float*)d_in[12];
    float* out = (float*)d_out;
    float* ws = (float*)d_ws;

    float* nf     = ws + NF_OFF;
    float* wT1    = ws + WT1_OFF;
    float* wT2    = ws + WT2_OFF;
    float* imgs_p = ws + IMGSP_OFF;
    float* pool1p = ws + POOL1P_OFF;
    float* pool2  = ws + POOL2_OFF;

    k_wt   <<<8, 256, 0, stream>>>(c1w, c2w, wT1, wT2);
    k_zero <<<(ZERO_N4 + 255) / 256, 256, 0, stream>>>(imgs_p);
    k_filt <<<4000, 256, 0, stream>>>(x, w1, b1, w2, b2, nf, out + BATCH * NCLS);
    k_pimg <<<BATCH * 2, 256, 0, stream>>>(nf, pi0, pi1, imgs_p);
    k_conv1<<<1250, 256, 0, stream>>>(imgs_p, wT1, c1b, pool1p);
    k_conv2<<<2500, 64, 0, stream>>>(pool1p, wT2, c2b, pool2);
    k_fc   <<<BATCH * NCLS, 256, 0, stream>>>(pool2, oww, owb, out);
}

// Round 4
// 173.924 us; speedup vs baseline: 1.2478x; 1.2478x over previous
//
#include <hip/hip_runtime.h>
#include <hip/hip_bf16.h>

#define N_NODES 16000
#define IN_F 128
#define HID 64
#define BATCH 32
#define NPAIR 128
#define DRES 100
#define NCLS 10

// workspace layout (float offsets)
#define NF_OFF     0
#define WT1_OFF    16000                     // [2 ic][25 tap][16 oc]
#define WT2_OFF    (16000 + 800)             // [16 ic][25 tap][32 oc]
#define INV_OFF    (16000 + 800 + 12800)     // [64] per-(b,c) 1/max
#define IMGSP_OFF  (INV_OFF + 64)            // [32][2][104][104] padded
#define POOL1P_OFF (IMGSP_OFF + 32*2*104*104)   // [32][16][54][56] padded
#define POOL2_OFF  (POOL1P_OFF + 32*16*54*56)   // [32][32][25][25]
#define ZERO_N4    ((32*2*104*104 + 32*16*54*56) / 4)

// ---------------- Kernel W: weight transpose ----------------
__global__ __launch_bounds__(256) void k_wt(const float* __restrict__ c1w,
    const float* __restrict__ c2w, float* __restrict__ wT1, float* __restrict__ wT2)
{
    int t = blockIdx.x * 256 + threadIdx.x;
    for (int i = t; i < 800; i += 256 * 8) {
        int ic = i / 400, tap = (i / 16) % 25, oc = i % 16;
        wT1[i] = c1w[(oc * 2 + ic) * 25 + tap];
    }
    for (int i = t; i < 12800; i += 256 * 8) {
        int ic = i / 800, tap = (i / 32) % 25, oc = i % 32;
        wT2[i] = c2w[(oc * 16 + ic) * 25 + tap];
    }
}

// ---------------- Kernel Z: zero padded activation buffers ----------------
__global__ __launch_bounds__(256) void k_zero(float* __restrict__ dst)
{
    int i = blockIdx.x * 256 + threadIdx.x;
    if (i < ZERO_N4) ((float4*)dst)[i] = make_float4(0.f, 0.f, 0.f, 0.f);
}

// ---------------- Kernel A: node filtration MLP (4 nodes per wave) ----------------
__global__ __launch_bounds__(256) void k_filt(const float* __restrict__ x,
    const float* __restrict__ w1, const float* __restrict__ b1,
    const float* __restrict__ w2, const float* __restrict__ b2,
    float* __restrict__ nf, float* __restrict__ out_nf)
{
    int t = threadIdx.x, wave = t >> 6, lane = t & 63;
    int n0 = blockIdx.x * 16 + wave * 4;
    const float* x0 = x + (size_t)n0 * IN_F;
    float a0 = 0.f, a1 = 0.f, a2 = 0.f, a3 = 0.f;
    #pragma unroll 4
    for (int k = 0; k < IN_F; ++k) {
        float wv = w1[k * HID + lane];
        a0 = fmaf(x0[k], wv, a0);
        a1 = fmaf(x0[k + IN_F], wv, a1);
        a2 = fmaf(x0[k + 2 * IN_F], wv, a2);
        a3 = fmaf(x0[k + 3 * IN_F], wv, a3);
    }
    float bb = b1[lane], w2v = w2[lane];
    float p0 = fmaxf(a0 + bb, 0.f) * w2v;
    float p1 = fmaxf(a1 + bb, 0.f) * w2v;
    float p2 = fmaxf(a2 + bb, 0.f) * w2v;
    float p3 = fmaxf(a3 + bb, 0.f) * w2v;
    #pragma unroll
    for (int off = 32; off > 0; off >>= 1) {
        p0 += __shfl_xor(p0, off, 64);
        p1 += __shfl_xor(p1, off, 64);
        p2 += __shfl_xor(p2, off, 64);
        p3 += __shfl_xor(p3, off, 64);
    }
    if (lane == 0) {
        float bv = b2[0];
        float f0 = 1.f / (1.f + expf(-(p0 + bv)));
        float f1 = 1.f / (1.f + expf(-(p1 + bv)));
        float f2 = 1.f / (1.f + expf(-(p2 + bv)));
        float f3 = 1.f / (1.f + expf(-(p3 + bv)));
        nf[n0] = f0; nf[n0 + 1] = f1; nf[n0 + 2] = f2; nf[n0 + 3] = f3;
        out_nf[n0] = f0; out_nf[n0 + 1] = f1; out_nf[n0 + 2] = f2; out_nf[n0 + 3] = f3;
    }
}

// ---------------- Kernel B: persistence image partial accumulate ----------------
// 256 blocks: (img 0..63) x (quarter q 0..3), 32 pairs each, atomicAdd into imgs_p.
// XCD-swizzle: img = (g&7)*8 + ((g>>3)&7) keeps one img's 4 blocks spread, imgs per XCD contiguous.
__global__ __launch_bounds__(256) void k_pimg(const float* __restrict__ nf,
    const int* __restrict__ pi0, const int* __restrict__ pi1,
    float* __restrict__ imgs_p)
{
    int g = blockIdx.x;
    int img = (g & 7) * 8 + ((g >> 3) & 7);
    int q = g >> 6;
    int b = img >> 1, c = img & 1;
    const int* pi = c ? pi1 : pi0;
    __shared__ float sb[32], sp[32];
    int t = threadIdx.x;
    if (t < 32) {
        int p = q * 32 + t;
        int i0 = pi[(b * NPAIR + p) * 2 + 0];
        int i1 = pi[(b * NPAIR + p) * 2 + 1];
        float f0 = nf[i0], f1 = nf[i1];
        sb[t] = f0;
        sp[t] = f1 - f0;
    }
    __syncthreads();
    if (t >= 169) return;
    int ti = t / 13, tj = t % 13;
    float ci[8], cj[8];
    #pragma unroll
    for (int r = 0; r < 8; ++r) {
        ci[r] = (float)(ti + 13 * r) * 0.01f;
        cj[r] = (float)(tj + 13 * r) * 0.01f;
    }
    float acc[8][8];
    #pragma unroll
    for (int r = 0; r < 8; ++r)
        #pragma unroll
        for (int s = 0; s < 8; ++s) acc[r][s] = 0.f;
    for (int p = 0; p < 32; ++p) {
        float bb = sb[p], pp = sp[p];
        float eb[8], ep[8];
        #pragma unroll
        for (int r = 0; r < 8; ++r) { float d = bb - ci[r]; eb[r] = __expf(-d * d); }
        #pragma unroll
        for (int s = 0; s < 8; ++s) { float d = pp - cj[s]; ep[s] = __expf(-d * d); }
        #pragma unroll
        for (int r = 0; r < 8; ++r)
            #pragma unroll
            for (int s = 0; s < 8; ++s)
                acc[r][s] = fmaf(eb[r], ep[s], acc[r][s]);
    }
    float* dst = imgs_p + (size_t)img * 10816 + 2 * 104 + 2;
    #pragma unroll
    for (int r = 0; r < 8; ++r) {
        int i = ti + 13 * r;
        if (i < DRES) {
            #pragma unroll
            for (int s = 0; s < 8; ++s) {
                int j = tj + 13 * s;
                if (j < DRES) atomicAdd(&dst[i * 104 + j], acc[r][s]);
            }
        }
    }
}

// ---------------- Kernel M: per-image max -> inv ----------------
__global__ __launch_bounds__(256) void k_pmax(const float* __restrict__ imgs_p,
    float* __restrict__ inv)
{
    int img = blockIdx.x;
    const float4* src = (const float4*)(imgs_p + (size_t)img * 10816);
    int t = threadIdx.x;
    float m = 0.f;
    for (int k = t; k < 2704; k += 256) {
        float4 v = src[k];
        m = fmaxf(m, fmaxf(fmaxf(v.x, v.y), fmaxf(v.z, v.w)));
    }
    #pragma unroll
    for (int off = 32; off > 0; off >>= 1)
        m = fmaxf(m, __shfl_xor(m, off, 64));
    __shared__ float wm[4];
    if ((t & 63) == 0) wm[t >> 6] = m;
    __syncthreads();
    if (t == 0) {
        float bm = fmaxf(fmaxf(wm[0], wm[1]), fmaxf(wm[2], wm[3]));
        inv[img] = 1.f / bm;
    }
}

// ---------------- Kernel C: conv1 + relu + maxpool2 ----------------
// 256 blocks: b=(g&7)*4+((g>>3)&3), rest=g>>5: ocg=rest&3, qh=rest>>2.
// 250 active threads: ow=t%50, slot=t/50; 5 pooled rows each.
__global__ __launch_bounds__(256) void k_conv1(const float* __restrict__ imgs_p,
    const float* __restrict__ wT1, const float* __restrict__ cb,
    const float* __restrict__ inv, float* __restrict__ pool1p)
{
    int g = blockIdx.x;
    int b = (g & 7) * 4 + ((g >> 3) & 3);
    int rest = g >> 5;
    int ocg = rest & 3, qh = rest >> 2;
    int t = threadIdx.x;
    if (t >= 250) return;
    int ow = t % 50, slot = t / 50;
    int oh0 = qh * 25 + slot * 5;
    float sc0 = inv[b * 2 + 0], sc1 = inv[b * 2 + 1];
    float4 bias4 = *(const float4*)(cb + ocg * 4);
    float bv[4] = {bias4.x, bias4.y, bias4.z, bias4.w};
    for (int pr = 0; pr < 5; ++pr) {
        int oh = oh0 + pr;
        float acc[4][2][2] = {};
        #pragma unroll
        for (int ic = 0; ic < 2; ++ic) {
            float sc = ic ? sc1 : sc0;
            const float* base = imgs_p + ((size_t)(b * 2 + ic) * 104 + 2 * oh) * 104 + 2 * ow;
            float p[6][6];
            #pragma unroll
            for (int r = 0; r < 6; ++r) {
                const float* rp = base + r * 104;
                float2 u0 = *(const float2*)rp;
                float2 u1 = *(const float2*)(rp + 2);
                float2 u2 = *(const float2*)(rp + 4);
                p[r][0] = u0.x * sc; p[r][1] = u0.y * sc; p[r][2] = u1.x * sc;
                p[r][3] = u1.y * sc; p[r][4] = u2.x * sc; p[r][5] = u2.y * sc;
            }
            const float* wrow = wT1 + ic * 400 + ocg * 4;
            #pragma unroll
            for (int kh = 0; kh < 5; ++kh)
                #pragma unroll
                for (int kw = 0; kw < 5; ++kw) {
                    float4 wv = *(const float4*)(wrow + (kh * 5 + kw) * 16);
                    #pragma unroll
                    for (int py = 0; py < 2; ++py)
                        #pragma unroll
                        for (int px = 0; px < 2; ++px) {
                            float v = p[kh + py][kw + px];
                            acc[0][py][px] = fmaf(v, wv.x, acc[0][py][px]);
                            acc[1][py][px] = fmaf(v, wv.y, acc[1][py][px]);
                            acc[2][py][px] = fmaf(v, wv.z, acc[2][py][px]);
                            acc[3][py][px] = fmaf(v, wv.w, acc[3][py][px]);
                        }
                }
        }
        #pragma unroll
        for (int o = 0; o < 4; ++o) {
            float m = fmaxf(fmaxf(acc[o][0][0], acc[o][0][1]),
                            fmaxf(acc[o][1][0], acc[o][1][1]));
            pool1p[((size_t)(b * 16 + ocg * 4 + o) * 54 + oh + 2) * 56 + ow + 2] =
                fmaxf(m + bv[o], 0.f);
        }
    }
}

// ---------------- Kernel D: conv2 + relu + maxpool2 ----------------
// 256 blocks: b=(g&7)*4+((g>>3)&3), ocg=g>>5. 169 active threads,
// thread = 4 oc x 4x4 conv outputs (2x2 pooled). Ping-pong patch buffers.
__global__ __launch_bounds__(256) void k_conv2(const float* __restrict__ pool1p,
    const float* __restrict__ wT2, const float* __restrict__ cb,
    float* __restrict__ pool2)
{
    int g = blockIdx.x;
    int b = (g & 7) * 4 + ((g >> 3) & 3);
    int ocg = g >> 5;
    int t = threadIdx.x;
    if (t >= 169) return;
    int ty = t / 13, tx = t % 13;
    float acc[4][4][4] = {};
    float4 pA[8][2], pB[8][2];

    auto LOADP = [&](float4 (&P)[8][2], int ic) {
        const float* bs = pool1p + (size_t)(b * 16 + ic) * 3024 + 4 * tx;
        #pragma unroll
        for (int r = 0; r < 8; ++r) {
            int rr = 4 * ty + r;
            rr = rr > 53 ? 53 : rr;   // ty=12 rows 6,7 feed clipped outputs only
            const float* rp = bs + rr * 56;
            P[r][0] = *(const float4*)rp;
            P[r][1] = *(const float4*)(rp + 4);
        }
    };
    auto FMAIC = [&](float4 (&P)[8][2], int ic) {
        float pr[8][8];
        #pragma unroll
        for (int r = 0; r < 8; ++r) {
            pr[r][0] = P[r][0].x; pr[r][1] = P[r][0].y;
            pr[r][2] = P[r][0].z; pr[r][3] = P[r][0].w;
            pr[r][4] = P[r][1].x; pr[r][5] = P[r][1].y;
            pr[r][6] = P[r][1].z; pr[r][7] = P[r][1].w;
        }
        const float* wrow = wT2 + ic * 800 + ocg * 4;
        #pragma unroll
        for (int kh = 0; kh < 5; ++kh)
            #pragma unroll
            for (int kw = 0; kw < 5; ++kw) {
                float4 wv = *(const float4*)(wrow + (kh * 5 + kw) * 32);
                #pragma unroll
                for (int cy = 0; cy < 4; ++cy)
                    #pragma unroll
                    for (int cx = 0; cx < 4; ++cx) {
                        float v = pr[kh + cy][kw + cx];
                        acc[0][cy][cx] = fmaf(v, wv.x, acc[0][cy][cx]);
                        acc[1][cy][cx] = fmaf(v, wv.y, acc[1][cy][cx]);
                        acc[2][cy][cx] = fmaf(v, wv.z, acc[2][cy][cx]);
                        acc[3][cy][cx] = fmaf(v, wv.w, acc[3][cy][cx]);
                    }
            }
    };

    LOADP(pA, 0);
    #pragma unroll 1
    for (int ic = 0; ic < 16; ic += 2) {
        LOADP(pB, ic + 1);
        FMAIC(pA, ic);
        if (ic + 2 < 16) LOADP(pA, ic + 2);
        FMAIC(pB, ic + 1);
    }

    float4 bias4 = *(const float4*)(cb + ocg * 4);
    float bv[4] = {bias4.x, bias4.y, bias4.z, bias4.w};
    #pragma unroll
    for (int o = 0; o < 4; ++o)
        #pragma unroll
        for (int py2 = 0; py2 < 2; ++py2)
            #pragma unroll
            for (int px2 = 0; px2 < 2; ++px2) {
                int cy = 2 * py2, cx = 2 * px2;
                float m = fmaxf(fmaxf(acc[o][cy][cx], acc[o][cy][cx + 1]),
                                fmaxf(acc[o][cy + 1][cx], acc[o][cy + 1][cx + 1]));
                int py = 2 * ty + py2, px = 2 * tx + px2;
                if (py < 25 && px < 25)
                    pool2[((size_t)(b * 32 + ocg * 4 + o) * 25 + py) * 25 + px] =
                        fmaxf(m + bv[o], 0.f);
            }
}

// ---------------- Kernel E: final linear (float4) ----------------
__global__ __launch_bounds__(256) void k_fc(const float* __restrict__ pool2,
    const float* __restrict__ oww, const float* __restrict__ ob,
    float* __restrict__ yhat)
{
    int cls = blockIdx.x / BATCH, b = blockIdx.x % BATCH;
    int t = threadIdx.x;
    const float4* y = (const float4*)(pool2 + (size_t)b * 20000);
    const float4* w = (const float4*)(oww + (size_t)cls * 20000);
    float acc = 0.f;
    for (int k = t; k < 5000; k += 256) {
        float4 a = y[k], ww = w[k];
        acc += a.x * ww.x + a.y * ww.y + a.z * ww.z + a.w * ww.w;
    }
    #pragma unroll
    for (int off = 32; off > 0; off >>= 1)
        acc += __shfl_xor(acc, off, 64);
    __shared__ float part[4];
    if ((t & 63) == 0) part[t >> 6] = acc;
    __syncthreads();
    if (t == 0)
        yhat[b * NCLS + cls] = part[0] + part[1] + part[2] + part[3] + ob[cls];
}

extern "C" void kernel_launch(void* const* d_in, const int* in_sizes, int n_in,
                              void* d_out, int out_size, void* d_ws, size_t ws_size,
                              hipStream_t stream)
{
    const float* x   = (const float*)d_in[0];
    const int*   pi0 = (const int*)d_in[1];
    const int*   pi1 = (const int*)d_in[2];
    const float* w1  = (const float*)d_in[3];
    const float* b1  = (const float*)d_in[4];
    const float* w2  = (const float*)d_in[5];
    const float* b2  = (const float*)d_in[6];
    const float* c1w = (const float*)d_in[7];
    const float* c1b = (const float*)d_in[8];
    const float* c2w = (const float*)d_in[9];
    const float* c2b = (const float*)d_in[10];
    const float* oww = (const float*)d_in[11];
    const float* owb = (const float*)d_in[12];
    float* out = (float*)d_out;
    float* ws = (float*)d_ws;

    float* nf     = ws + NF_OFF;
    float* wT1    = ws + WT1_OFF;
    float* wT2    = ws + WT2_OFF;
    float* inv    = ws + INV_OFF;
    float* imgs_p = ws + IMGSP_OFF;
    float* pool1p = ws + POOL1P_OFF;
    float* pool2  = ws + POOL2_OFF;

    k_wt   <<<8, 256, 0, stream>>>(c1w, c2w, wT1, wT2);
    k_zero <<<(ZERO_N4 + 255) / 256, 256, 0, stream>>>(imgs_p);
    k_filt <<<1000, 256, 0, stream>>>(x, w1, b1, w2, b2, nf, out + BATCH * NCLS);
    k_pimg <<<256, 256, 0, stream>>>(nf, pi0, pi1, imgs_p);
    k_pmax <<<64, 256, 0, stream>>>(imgs_p, inv);
    k_conv1<<<256, 256, 0, stream>>>(imgs_p, wT1, c1b, inv, pool1p);
    k_conv2<<<256, 256, 0, stream>>>(pool1p, wT2, c2b, pool2);
    k_fc   <<<BATCH * NCLS, 256, 0, stream>>>(pool2, oww, owb, out);
}

// Round 5
// 138.500 us; speedup vs baseline: 1.5670x; 1.2558x over previous
//
#include <hip/hip_runtime.h>
#include <hip/hip_bf16.h>

#define N_NODES 16000
#define IN_F 128
#define HID 64
#define BATCH 32
#define NPAIR 128
#define DRES 100
#define NCLS 10

// workspace layout (float offsets)
#define NF_OFF     0
#define WT1_OFF    16000                     // [2 ic][25 tap][16 oc]
#define WT2_OFF    (16000 + 800)             // [16 ic][25 tap][32 oc]
#define INV_OFF    (16000 + 800 + 12800)     // [64] per-(b,c) 1/max
#define IMGSP_OFF  (INV_OFF + 64)            // [32][2][104][104] padded
#define POOL1P_OFF (IMGSP_OFF + 32*2*104*104)   // [32][16][54][56] padded
#define POOL2_OFF  (POOL1P_OFF + 32*16*54*56)   // [32][32][25][25]
#define ZERO_N4    ((32*2*104*104 + 32*16*54*56) / 4)

// float2 patch element access (compile-time index under full unroll)
#define PV(P, r, c) (((c) & 1) ? P[(r)*3 + ((c)>>1)].y : P[(r)*3 + ((c)>>1)].x)

// ---------------- Kernel I: weight transpose + zero padded buffers ----------------
__global__ __launch_bounds__(256) void k_init(const float* __restrict__ c1w,
    const float* __restrict__ c2w, float* __restrict__ wT1, float* __restrict__ wT2,
    float* __restrict__ zbase)
{
    int bx = blockIdx.x, t = threadIdx.x;
    if (bx == 0) {
        for (int i = t; i < 800; i += 256) {
            int ic = i / 400, tap = (i / 16) % 25, oc = i % 16;
            wT1[i] = c1w[(oc * 2 + ic) * 25 + tap];
        }
    } else if (bx == 1) {
        for (int i = t; i < 12800; i += 256) {
            int ic = i / 800, tap = (i / 32) % 25, oc = i % 32;
            wT2[i] = c2w[(oc * 16 + ic) * 25 + tap];
        }
    } else {
        int i = (bx - 2) * 256 + t;
        if (i < ZERO_N4) ((float4*)zbase)[i] = make_float4(0.f, 0.f, 0.f, 0.f);
    }
}

// ---------------- Kernel A: node filtration MLP (4 nodes per wave) ----------------
__global__ __launch_bounds__(256) void k_filt(const float* __restrict__ x,
    const float* __restrict__ w1, const float* __restrict__ b1,
    const float* __restrict__ w2, const float* __restrict__ b2,
    float* __restrict__ nf, float* __restrict__ out_nf)
{
    int t = threadIdx.x, wave = t >> 6, lane = t & 63;
    int n0 = blockIdx.x * 16 + wave * 4;
    const float* x0 = x + (size_t)n0 * IN_F;
    float a0 = 0.f, a1 = 0.f, a2 = 0.f, a3 = 0.f;
    #pragma unroll 4
    for (int k = 0; k < IN_F; ++k) {
        float wv = w1[k * HID + lane];
        a0 = fmaf(x0[k], wv, a0);
        a1 = fmaf(x0[k + IN_F], wv, a1);
        a2 = fmaf(x0[k + 2 * IN_F], wv, a2);
        a3 = fmaf(x0[k + 3 * IN_F], wv, a3);
    }
    float bb = b1[lane], w2v = w2[lane];
    float p0 = fmaxf(a0 + bb, 0.f) * w2v;
    float p1 = fmaxf(a1 + bb, 0.f) * w2v;
    float p2 = fmaxf(a2 + bb, 0.f) * w2v;
    float p3 = fmaxf(a3 + bb, 0.f) * w2v;
    #pragma unroll
    for (int off = 32; off > 0; off >>= 1) {
        p0 += __shfl_xor(p0, off, 64);
        p1 += __shfl_xor(p1, off, 64);
        p2 += __shfl_xor(p2, off, 64);
        p3 += __shfl_xor(p3, off, 64);
    }
    if (lane == 0) {
        float bv = b2[0];
        float f0 = 1.f / (1.f + expf(-(p0 + bv)));
        float f1 = 1.f / (1.f + expf(-(p1 + bv)));
        float f2 = 1.f / (1.f + expf(-(p2 + bv)));
        float f3 = 1.f / (1.f + expf(-(p3 + bv)));
        nf[n0] = f0; nf[n0 + 1] = f1; nf[n0 + 2] = f2; nf[n0 + 3] = f3;
        out_nf[n0] = f0; out_nf[n0 + 1] = f1; out_nf[n0 + 2] = f2; out_nf[n0 + 3] = f3;
    }
}

// ---------------- Kernel B: persistence image partial accumulate ----------------
// 256 blocks: (img, quarter). 4 quarter-blocks of an img share g%8 -> same XCD L2.
__global__ __launch_bounds__(256) void k_pimg(const float* __restrict__ nf,
    const int* __restrict__ pi0, const int* __restrict__ pi1,
    float* __restrict__ imgs_p)
{
    int g = blockIdx.x;
    int img = (g & 7) * 8 + ((g >> 3) & 7);
    int q = g >> 6;
    int b = img >> 1, c = img & 1;
    const int* pi = c ? pi1 : pi0;
    __shared__ float sb[32], sp[32];
    int t = threadIdx.x;
    if (t < 32) {
        int p = q * 32 + t;
        int i0 = pi[(b * NPAIR + p) * 2 + 0];
        int i1 = pi[(b * NPAIR + p) * 2 + 1];
        float f0 = nf[i0], f1 = nf[i1];
        sb[t] = f0;
        sp[t] = f1 - f0;
    }
    __syncthreads();
    if (t >= 169) return;
    int ti = t / 13, tj = t % 13;
    float ci[8], cj[8];
    #pragma unroll
    for (int r = 0; r < 8; ++r) {
        ci[r] = (float)(ti + 13 * r) * 0.01f;
        cj[r] = (float)(tj + 13 * r) * 0.01f;
    }
    float acc[8][8];
    #pragma unroll
    for (int r = 0; r < 8; ++r)
        #pragma unroll
        for (int s = 0; s < 8; ++s) acc[r][s] = 0.f;
    for (int p = 0; p < 32; ++p) {
        float bb = sb[p], pp = sp[p];
        float eb[8], ep[8];
        #pragma unroll
        for (int r = 0; r < 8; ++r) { float d = bb - ci[r]; eb[r] = __expf(-d * d); }
        #pragma unroll
        for (int s = 0; s < 8; ++s) { float d = pp - cj[s]; ep[s] = __expf(-d * d); }
        #pragma unroll
        for (int r = 0; r < 8; ++r)
            #pragma unroll
            for (int s = 0; s < 8; ++s)
                acc[r][s] = fmaf(eb[r], ep[s], acc[r][s]);
    }
    float* dst = imgs_p + (size_t)img * 10816 + 2 * 104 + 2;
    #pragma unroll
    for (int r = 0; r < 8; ++r) {
        int i = ti + 13 * r;
        if (i < DRES) {
            #pragma unroll
            for (int s = 0; s < 8; ++s) {
                int j = tj + 13 * s;
                if (j < DRES) atomicAdd(&dst[i * 104 + j], acc[r][s]);
            }
        }
    }
}

// ---------------- Kernel M: per-image max -> inv ----------------
__global__ __launch_bounds__(256) void k_pmax(const float* __restrict__ imgs_p,
    float* __restrict__ inv)
{
    int img = blockIdx.x;
    const float4* src = (const float4*)(imgs_p + (size_t)img * 10816);
    int t = threadIdx.x;
    float m = 0.f;
    for (int k = t; k < 2704; k += 256) {
        float4 v = src[k];
        m = fmaxf(m, fmaxf(fmaxf(v.x, v.y), fmaxf(v.z, v.w)));
    }
    #pragma unroll
    for (int off = 32; off > 0; off >>= 1)
        m = fmaxf(m, __shfl_xor(m, off, 64));
    __shared__ float wm[4];
    if ((t & 63) == 0) wm[t >> 6] = m;
    __syncthreads();
    if (t == 0) {
        float bm = fmaxf(fmaxf(wm[0], wm[1]), fmaxf(wm[2], wm[3]));
        inv[img] = 1.f / bm;
    }
}

// ---------------- Kernel C: conv1 + relu + maxpool2 ----------------
// 1280 blocks: (b, ocg in 4, rowgroup in 10). 250 active threads = 50 ow x 5 rows.
// thread = 4 oc x 1 pooled output. inv-scale folded into epilogue via per-ic accs.
__global__ __launch_bounds__(256) void k_conv1(const float* __restrict__ imgs_p,
    const float* __restrict__ wT1, const float* __restrict__ cb,
    const float* __restrict__ inv, float* __restrict__ pool1p)
{
    int g = blockIdx.x;
    int b = (g & 7) * 4 + ((g >> 3) & 3);
    int ocg = (g >> 5) & 3;
    int rg = g >> 7;
    int t = threadIdx.x;
    if (t >= 250) return;
    int ow = t % 50, oh = rg * 5 + t / 50;

    float2 PA[18], PB[18];
    {
        const float* bs = imgs_p + (size_t)(b * 2 + 0) * 10816 + (2 * oh) * 104 + 2 * ow;
        #pragma unroll
        for (int r = 0; r < 6; ++r) {
            const float* rp = bs + r * 104;
            PA[r * 3 + 0] = *(const float2*)rp;
            PA[r * 3 + 1] = *(const float2*)(rp + 2);
            PA[r * 3 + 2] = *(const float2*)(rp + 4);
        }
        const float* bs1 = bs + 10816;
        #pragma unroll
        for (int r = 0; r < 6; ++r) {
            const float* rp = bs1 + r * 104;
            PB[r * 3 + 0] = *(const float2*)rp;
            PB[r * 3 + 1] = *(const float2*)(rp + 2);
            PB[r * 3 + 2] = *(const float2*)(rp + 4);
        }
    }
    float acc0[4][2][2] = {}, acc1[4][2][2] = {};
    const float* w0 = wT1 + ocg * 4;
    const float* w1r = wT1 + 400 + ocg * 4;
    #pragma unroll
    for (int kh = 0; kh < 5; ++kh)
        #pragma unroll
        for (int kw = 0; kw < 5; ++kw) {
            float4 wa = *(const float4*)(w0 + (kh * 5 + kw) * 16);
            float4 wb = *(const float4*)(w1r + (kh * 5 + kw) * 16);
            #pragma unroll
            for (int j = 0; j < 2; ++j)
                #pragma unroll
                for (int i = 0; i < 2; ++i) {
                    float va = PV(PA, kh + j, kw + i);
                    float vb = PV(PB, kh + j, kw + i);
                    acc0[0][j][i] = fmaf(va, wa.x, acc0[0][j][i]);
                    acc0[1][j][i] = fmaf(va, wa.y, acc0[1][j][i]);
                    acc0[2][j][i] = fmaf(va, wa.z, acc0[2][j][i]);
                    acc0[3][j][i] = fmaf(va, wa.w, acc0[3][j][i]);
                    acc1[0][j][i] = fmaf(vb, wb.x, acc1[0][j][i]);
                    acc1[1][j][i] = fmaf(vb, wb.y, acc1[1][j][i]);
                    acc1[2][j][i] = fmaf(vb, wb.z, acc1[2][j][i]);
                    acc1[3][j][i] = fmaf(vb, wb.w, acc1[3][j][i]);
                }
        }
    float sc0 = inv[b * 2 + 0], sc1 = inv[b * 2 + 1];
    float4 bias4 = *(const float4*)(cb + ocg * 4);
    float bv[4] = {bias4.x, bias4.y, bias4.z, bias4.w};
    #pragma unroll
    for (int o = 0; o < 4; ++o) {
        float v00 = fmaf(sc1, acc1[o][0][0], sc0 * acc0[o][0][0]);
        float v01 = fmaf(sc1, acc1[o][0][1], sc0 * acc0[o][0][1]);
        float v10 = fmaf(sc1, acc1[o][1][0], sc0 * acc0[o][1][0]);
        float v11 = fmaf(sc1, acc1[o][1][1], sc0 * acc0[o][1][1]);
        float m = fmaxf(fmaxf(v00, v01), fmaxf(v10, v11));
        pool1p[((size_t)(b * 16 + ocg * 4 + o) * 54 + oh + 2) * 56 + ow + 2] =
            fmaxf(m + bv[o], 0.f);
    }
}

// ---------------- Kernel D: conv2 + relu + maxpool2 ----------------
// 256 blocks (b, ocg), 640 threads (625 active), thread = 4 oc x 1 pooled output.
__global__ __launch_bounds__(640) void k_conv2(const float* __restrict__ pool1p,
    const float* __restrict__ wT2, const float* __restrict__ cb,
    float* __restrict__ pool2)
{
    int g = blockIdx.x;
    int b = (g & 7) * 4 + ((g >> 3) & 3);
    int ocg = g >> 5;
    int t = threadIdx.x;
    if (t >= 625) return;
    int py = t / 25, px = t % 25;
    float acc[4][2][2] = {};
    float2 PA[18], PB[18];

    auto LOADP = [&](float2 (&P)[18], int ic) {
        const float* bs = pool1p + (size_t)(b * 16 + ic) * 3024 + (2 * py) * 56 + 2 * px;
        #pragma unroll
        for (int r = 0; r < 6; ++r) {
            const float* rp = bs + r * 56;
            P[r * 3 + 0] = *(const float2*)rp;
            P[r * 3 + 1] = *(const float2*)(rp + 2);
            P[r * 3 + 2] = *(const float2*)(rp + 4);
        }
    };
    auto FMAIC = [&](float2 (&P)[18], int ic) {
        const float* wrow = wT2 + ic * 800 + ocg * 4;
        #pragma unroll
        for (int kh = 0; kh < 5; ++kh)
            #pragma unroll
            for (int kw = 0; kw < 5; ++kw) {
                float4 wv = *(const float4*)(wrow + (kh * 5 + kw) * 32);
                #pragma unroll
                for (int j = 0; j < 2; ++j)
                    #pragma unroll
                    for (int i = 0; i < 2; ++i) {
                        float v = PV(P, kh + j, kw + i);
                        acc[0][j][i] = fmaf(v, wv.x, acc[0][j][i]);
                        acc[1][j][i] = fmaf(v, wv.y, acc[1][j][i]);
                        acc[2][j][i] = fmaf(v, wv.z, acc[2][j][i]);
                        acc[3][j][i] = fmaf(v, wv.w, acc[3][j][i]);
                    }
            }
    };

    LOADP(PA, 0);
    #pragma unroll 1
    for (int ic = 0; ic < 16; ic += 2) {
        LOADP(PB, ic + 1);
        FMAIC(PA, ic);
        if (ic + 2 < 16) LOADP(PA, ic + 2);
        FMAIC(PB, ic + 1);
    }

    float4 bias4 = *(const float4*)(cb + ocg * 4);
    float bv[4] = {bias4.x, bias4.y, bias4.z, bias4.w};
    #pragma unroll
    for (int o = 0; o < 4; ++o) {
        float m = fmaxf(fmaxf(acc[o][0][0], acc[o][0][1]),
                        fmaxf(acc[o][1][0], acc[o][1][1]));
        pool2[((size_t)(b * 32 + ocg * 4 + o) * 25 + py) * 25 + px] =
            fmaxf(m + bv[o], 0.f);
    }
}

// ---------------- Kernel E: final linear (float4) ----------------
__global__ __launch_bounds__(256) void k_fc(const float* __restrict__ pool2,
    const float* __restrict__ oww, const float* __restrict__ ob,
    float* __restrict__ yhat)
{
    int cls = blockIdx.x / BATCH, b = blockIdx.x % BATCH;
    int t = threadIdx.x;
    const float4* y = (const float4*)(pool2 + (size_t)b * 20000);
    const float4* w = (const float4*)(oww + (size_t)cls * 20000);
    float acc = 0.f;
    for (int k = t; k < 5000; k += 256) {
        float4 a = y[k], ww = w[k];
        acc += a.x * ww.x + a.y * ww.y + a.z * ww.z + a.w * ww.w;
    }
    #pragma unroll
    for (int off = 32; off > 0; off >>= 1)
        acc += __shfl_xor(acc, off, 64);
    __shared__ float part[4];
    if ((t & 63) == 0) part[t >> 6] = acc;
    __syncthreads();
    if (t == 0)
        yhat[b * NCLS + cls] = part[0] + part[1] + part[2] + part[3] + ob[cls];
}

extern "C" void kernel_launch(void* const* d_in, const int* in_sizes, int n_in,
                              void* d_out, int out_size, void* d_ws, size_t ws_size,
                              hipStream_t stream)
{
    const float* x   = (const float*)d_in[0];
    const int*   pi0 = (const int*)d_in[1];
    const int*   pi1 = (const int*)d_in[2];
    const float* w1  = (const float*)d_in[3];
    const float* b1  = (const float*)d_in[4];
    const float* w2  = (const float*)d_in[5];
    const float* b2  = (const float*)d_in[6];
    const float* c1w = (const float*)d_in[7];
    const float* c1b = (const float*)d_in[8];
    const float* c2w = (const float*)d_in[9];
    const float* c2b = (const float*)d_in[10];
    const float* oww = (const float*)d_in[11];
    const float* owb = (const float*)d_in[12];
    float* out = (float*)d_out;
    float* ws = (float*)d_ws;

    float* nf     = ws + NF_OFF;
    float* wT1    = ws + WT1_OFF;
    float* wT2    = ws + WT2_OFF;
    float* inv    = ws + INV_OFF;
    float* imgs_p = ws + IMGSP_OFF;
    float* pool1p = ws + POOL1P_OFF;
    float* pool2  = ws + POOL2_OFF;

    k_init <<<2 + (ZERO_N4 + 255) / 256, 256, 0, stream>>>(c1w, c2w, wT1, wT2, imgs_p);
    k_filt <<<1000, 256, 0, stream>>>(x, w1, b1, w2, b2, nf, out + BATCH * NCLS);
    k_pimg <<<256, 256, 0, stream>>>(nf, pi0, pi1, imgs_p);
    k_pmax <<<64, 256, 0, stream>>>(imgs_p, inv);
    k_conv1<<<1280, 256, 0, stream>>>(imgs_p, wT1, c1b, inv, pool1p);
    k_conv2<<<256, 640, 0, stream>>>(pool1p, wT2, c2b, pool2);
    k_fc   <<<BATCH * NCLS, 256, 0, stream>>>(pool2, oww, owb, out);
}